// Round 2
// baseline (4882.240 us; speedup 1.0000x reference)
//
#include <hip/hip_runtime.h>
#include <math.h>

#define H 51
#define HR 52            // padded row length (pad slot = 0)
#define TSEEN 256
#define FUT 16
#define TTOT (TSEEN + FUT)
#define NB 4             // batches per block
#define THREADS 256
#define NBLOCKS (2048 / NB)   // 512 blocks -> 2 blocks/CU

typedef float v2f __attribute__((ext_vector_type(2)));

__device__ __forceinline__ float fast_rcp(float x) { return __builtin_amdgcn_rcpf(x); }

__device__ __forceinline__ float fast_tanh(float x) {
  // overflow-safe: e = exp(-2|x|) in (0,1]
  float e = __expf(-2.f * fabsf(x));
  return copysignf((1.f - e) * fast_rcp(1.f + e), x);
}

// broadcast quad slot S (0..3) to all 4 lanes of the quad via DPP quad_perm
template<int S>
__device__ __forceinline__ float qbc(float v) {
  return __int_as_float(__builtin_amdgcn_mov_dpp(__float_as_int(v), S * 0x55, 0xf, 0xf, true));
}

#define FMA2(acc, w, x, y) acc = __builtin_elementwise_fma((v2f){w, w}, (v2f){x, y}, acc)

__launch_bounds__(THREADS, 2)
__global__ void lstm2_kernel(const float* __restrict__ inp,
                             const float* __restrict__ Wih1,
                             const float* __restrict__ bih1,
                             const float* __restrict__ Whh1,
                             const float* __restrict__ bhh1,
                             const float* __restrict__ Wih2,
                             const float* __restrict__ bih2,
                             const float* __restrict__ Whh2,
                             const float* __restrict__ bhh2,
                             const float* __restrict__ Wlin,
                             const float* __restrict__ blin,
                             float* __restrict__ out)
{
  // h state: [parity][unit(padded)][batch]  — rows are 16B, reads are wave
  // broadcasts (conflict-free), writes are one float4 per unit.
  __shared__ __align__(16) float h1s[2][HR][NB];
  __shared__ __align__(16) float h2s[2][HR][NB];
  __shared__ __align__(16) float xs[TSEEN][NB];
  __shared__ __align__(16) float parts[2][4][NB];   // [parity][wave][batch]

  const int tid   = threadIdx.x;
  const int wv    = tid >> 6;
  const int lane  = tid & 63;
  const int g     = lane & 3;          // 0=i 1=f 2=g~ 3=o (PyTorch row blocks)
  const int u     = (wv << 4) + (lane >> 2);   // unit 0..63 (51 active)
  const bool on   = (u < H);
  const int uc    = on ? u : (H - 1);
  const int r     = g * H + uc;        // gate row in [0,204)
  const int baseb = blockIdx.x * NB;

  // ---- zero LDS state (both parities; pad rows stay 0 forever) ----
  for (int i = tid; i < 2 * HR * NB; i += THREADS) {
    (&h1s[0][0][0])[i] = 0.f;
    (&h2s[0][0][0])[i] = 0.f;
  }
  if (tid < 2 * 4 * NB) (&parts[0][0][0])[tid] = 0.f;

  // ---- stage inputs transposed: xs[t][b] ----
  for (int i = tid; i < TSEEN * NB; i += THREADS) {
    int t = i >> 2, b = i & 3;
    xs[t][b] = inp[(size_t)(baseb + b) * TSEEN + t];
  }

  // ---- per-thread register weights: one gate-row, both layers ----
  float A1[HR], A2[HR], A3[HR];
  #pragma unroll
  for (int k = 0; k < H; ++k) {
    A1[k] = on ? Whh1[r * H + k] : 0.f;
    A2[k] = on ? Wih2[r * H + k] : 0.f;
    A3[k] = on ? Whh2[r * H + k] : 0.f;
  }
  A1[H] = 0.f; A2[H] = 0.f; A3[H] = 0.f;
  const float wx = on ? Wih1[r] : 0.f;
  const float b1 = on ? (bih1[r] + bhh1[r]) : 0.f;
  const float b2 = on ? (bih2[r] + bhh2[r]) : 0.f;
  const float wl = (on && g == 0) ? Wlin[uc] : 0.f;
  const float bl = blin[0];
  const float es = (g == 2) ? -2.f : -1.f;   // exp scale: tanh uses e^-2|x|
  const bool isg = (g == 2);

  float c1[NB] = {0.f, 0.f, 0.f, 0.f};
  float c2[NB] = {0.f, 0.f, 0.f, 0.f};
  float fb[NB] = {0.f, 0.f, 0.f, 0.f};

  __syncthreads();

  #pragma unroll 1
  for (int t = 0; t < TTOT; ++t) {
    const int pw = t & 1;       // write parity this step
    const int pr = pw ^ 1;      // read parity (state from t-1)

    // ---- x for this step ----
    float x0, x1, x2, x3;
    if (t < TSEEN) {
      float4 xv = *(const float4*)&xs[t][0];
      x0 = xv.x; x1 = xv.y; x2 = xv.z; x3 = xv.w;
    } else {
      x0 = fb[0]; x1 = fb[1]; x2 = fb[2]; x3 = fb[3];
    }

    // ================= layer 1: a = b1 + wx*x + A1 . h1(t-1) =================
    v2f a01 = {b1, b1}, a23 = {b1, b1};
    v2f s01 = {0.f, 0.f}, s23 = {0.f, 0.f};
    FMA2(a01, wx, x0, x1);
    FMA2(a23, wx, x2, x3);
    #pragma unroll
    for (int k = 0; k < HR; k += 2) {
      float4 h0 = *(const float4*)&h1s[pr][k][0];
      float4 h1v = *(const float4*)&h1s[pr][k + 1][0];
      FMA2(a01, A1[k],     h0.x,  h0.y);
      FMA2(a23, A1[k],     h0.z,  h0.w);
      FMA2(s01, A1[k + 1], h1v.x, h1v.y);
      FMA2(s23, A1[k + 1], h1v.z, h1v.w);
    }
    a01 += s01; a23 += s23;

    float av1[NB] = {a01.x, a01.y, a23.x, a23.y};
    float h1n[NB];
    #pragma unroll
    for (int b = 0; b < NB; ++b) {
      float a  = av1[b];
      float xa = isg ? fabsf(a) : a;
      float e  = __expf(es * xa);
      float nm = isg ? (1.f - e) : 1.f;
      float v  = nm * fast_rcp(1.f + e);
      v = isg ? copysignf(v, a) : v;
      float vi = qbc<0>(v), vf = qbc<1>(v), vg = qbc<2>(v), vo = qbc<3>(v);
      c1[b]  = fmaf(vf, c1[b], vi * vg);
      h1n[b] = vo * fast_tanh(c1[b]);
    }
    if (g == 0 && on) {
      float4 hw; hw.x = h1n[0]; hw.y = h1n[1]; hw.z = h1n[2]; hw.w = h1n[3];
      *(float4*)&h1s[pw][u][0] = hw;
    }
    __syncthreads();   // barrier A — the only per-step barrier (seen phase)

    // deferred output write: out(t-1) for t-1 in [0,254]
    if (t >= 1 && t <= TSEEN - 1) {
      if (tid < NB) {
        float s = parts[pr][0][tid] + parts[pr][1][tid] +
                  parts[pr][2][tid] + parts[pr][3][tid] + bl;
        out[(size_t)(baseb + tid) * TTOT + (t - 1)] = s;
      }
    }

    // ============ layer 2: a = b2 + A2 . h1(t) + A3 . h2(t-1) ============
    v2f q01 = {b2, b2}, q23 = {b2, b2};
    v2f r01 = {0.f, 0.f}, r23 = {0.f, 0.f};
    #pragma unroll
    for (int k = 0; k < HR; k += 2) {
      float4 p1a = *(const float4*)&h1s[pw][k][0];
      float4 p1b = *(const float4*)&h1s[pw][k + 1][0];
      float4 p2a = *(const float4*)&h2s[pr][k][0];
      float4 p2b = *(const float4*)&h2s[pr][k + 1][0];
      FMA2(q01, A2[k],     p1a.x, p1a.y);
      FMA2(q23, A2[k],     p1a.z, p1a.w);
      FMA2(r01, A2[k + 1], p1b.x, p1b.y);
      FMA2(r23, A2[k + 1], p1b.z, p1b.w);
      FMA2(q01, A3[k],     p2a.x, p2a.y);
      FMA2(q23, A3[k],     p2a.z, p2a.w);
      FMA2(r01, A3[k + 1], p2b.x, p2b.y);
      FMA2(r23, A3[k + 1], p2b.z, p2b.w);
    }
    q01 += r01; q23 += r23;

    float av2[NB] = {q01.x, q01.y, q23.x, q23.y};
    float h2n[NB], pv[NB];
    #pragma unroll
    for (int b = 0; b < NB; ++b) {
      float a  = av2[b];
      float xa = isg ? fabsf(a) : a;
      float e  = __expf(es * xa);
      float nm = isg ? (1.f - e) : 1.f;
      float v  = nm * fast_rcp(1.f + e);
      v = isg ? copysignf(v, a) : v;
      float vi = qbc<0>(v), vf = qbc<1>(v), vg = qbc<2>(v), vo = qbc<3>(v);
      c2[b]  = fmaf(vf, c2[b], vi * vg);
      h2n[b] = vo * fast_tanh(c2[b]);
      pv[b]  = wl * h2n[b];
    }

    // head partial: sum over g==0 lanes of this wave (xor 4/8/16/32 butterfly)
    #pragma unroll
    for (int m = 4; m <= 32; m <<= 1) {
      #pragma unroll
      for (int b = 0; b < NB; ++b) pv[b] += __shfl_xor(pv[b], m, 64);
    }

    if (g == 0 && on) {
      float4 hw; hw.x = h2n[0]; hw.y = h2n[1]; hw.z = h2n[2]; hw.w = h2n[3];
      *(float4*)&h2s[pw][u][0] = hw;
    }
    if (lane == 0) {
      float4 pw4; pw4.x = pv[0]; pw4.y = pv[1]; pw4.z = pv[2]; pw4.w = pv[3];
      *(float4*)&parts[pw][wv][0] = pw4;
    }

    // feedback phase: need out(t) now (x(t+1) = out(t)); also write outs 255..271
    if (t >= TSEEN - 1) {
      __syncthreads();   // barrier B (17 steps only)
      #pragma unroll
      for (int b = 0; b < NB; ++b)
        fb[b] = parts[pw][0][b] + parts[pw][1][b] +
                parts[pw][2][b] + parts[pw][3][b] + bl;
      if (tid < NB) out[(size_t)(baseb + tid) * TTOT + t] = fb[tid];
    }
  }
}

extern "C" void kernel_launch(void* const* d_in, const int* in_sizes, int n_in,
                              void* d_out, int out_size, void* d_ws, size_t ws_size,
                              hipStream_t stream) {
  (void)in_sizes; (void)n_in; (void)d_ws; (void)ws_size; (void)out_size;
  const float* inp  = (const float*)d_in[0];
  const float* Wih1 = (const float*)d_in[1];
  const float* bih1 = (const float*)d_in[2];
  const float* Whh1 = (const float*)d_in[3];
  const float* bhh1 = (const float*)d_in[4];
  const float* Wih2 = (const float*)d_in[5];
  const float* bih2 = (const float*)d_in[6];
  const float* Whh2 = (const float*)d_in[7];
  const float* bhh2 = (const float*)d_in[8];
  const float* Wlin = (const float*)d_in[9];
  const float* blin = (const float*)d_in[10];
  float* outp = (float*)d_out;

  lstm2_kernel<<<NBLOCKS, THREADS, 0, stream>>>(
      inp, Wih1, bih1, Whh1, bhh1, Wih2, bih2, Whh2, bhh2, Wlin, blin, outp);
}

// Round 3
// 1216.511 us; speedup vs baseline: 4.0133x; 4.0133x over previous
//
#include <hip/hip_runtime.h>
#include <math.h>

#define H 51
#define KP 52            // k padded to 13 float4 chunks (pad = 0)
#define NKC 13
#define NROW 204         // 4*H gate rows
#define TSEEN 256
#define FUT 16
#define TTOT (TSEEN + FUT)
#define NBB 8            // batches per block
#define THREADS 512
#define NBLOCKS (2048 / NBB)   // 256 blocks -> 1 per CU

typedef float v2f __attribute__((ext_vector_type(2)));

__device__ __forceinline__ float fast_rcp(float x) { return __builtin_amdgcn_rcpf(x); }

__device__ __forceinline__ float fast_sig(float x) {
  float e = __expf(-x);
  return fast_rcp(1.f + e);          // rcp(inf)=0 -> saturates cleanly
}

__device__ __forceinline__ float fast_tanh(float x) {
  float e = __expf(-2.f * fabsf(x)); // e in (0,1] -> overflow-safe
  return copysignf((1.f - e) * fast_rcp(1.f + e), x);
}

// broadcast quad slot S (0..3) to all 4 lanes of the quad via DPP quad_perm
template<int S>
__device__ __forceinline__ float qbc(float v) {
  return __int_as_float(__builtin_amdgcn_mov_dpp(__float_as_int(v), S * 0x55, 0xf, 0xf, true));
}

__device__ __forceinline__ float sel4(bool q1, bool q2, bool q3,
                                      float a, float b, float c, float d) {
  float r = a;
  r = q1 ? b : r;
  r = q2 ? c : r;
  r = q3 ? d : r;
  return r;
}

#define FMA2(acc, w, x, y) acc = __builtin_elementwise_fma((v2f){w, w}, (v2f){x, y}, acc)

// quad transpose: each lane (gate g) holds its gate-row's values for batches
// 0..3; return gates i,f,g~,o for THIS lane's batch q (= lane&3).
__device__ __forceinline__ void gates_for_batch(v2f a01, v2f a23,
                                                bool q1, bool q2, bool q3,
                                                float& gi, float& gf,
                                                float& gg, float& go) {
  float b0 = a01.x, b1 = a01.y, b2 = a23.x, b3 = a23.y;
  float i0 = qbc<0>(b0), i1 = qbc<0>(b1), i2 = qbc<0>(b2), i3 = qbc<0>(b3);
  float f0 = qbc<1>(b0), f1 = qbc<1>(b1), f2 = qbc<1>(b2), f3 = qbc<1>(b3);
  float g0 = qbc<2>(b0), g1 = qbc<2>(b1), g2 = qbc<2>(b2), g3 = qbc<2>(b3);
  float o0 = qbc<3>(b0), o1 = qbc<3>(b1), o2 = qbc<3>(b2), o3 = qbc<3>(b3);
  gi = sel4(q1, q2, q3, i0, i1, i2, i3);
  gf = sel4(q1, q2, q3, f0, f1, f2, f3);
  gg = sel4(q1, q2, q3, g0, g1, g2, g3);
  go = sel4(q1, q2, q3, o0, o1, o2, o3);
}

__launch_bounds__(THREADS, 2)
__global__ void lstm2_kernel(const float* __restrict__ inp,
                             const float* __restrict__ Wih1,
                             const float* __restrict__ bih1,
                             const float* __restrict__ Whh1,
                             const float* __restrict__ bhh1,
                             const float* __restrict__ Wih2,
                             const float* __restrict__ bih2,
                             const float* __restrict__ Whh2,
                             const float* __restrict__ bhh2,
                             const float* __restrict__ Wlin,
                             const float* __restrict__ blin,
                             float* __restrict__ out)
{
  // weights: [mat][kc][row] float4 = W[row][4kc..4kc+3]; 127.3 KB
  __shared__ __align__(16) float4 WL[3 * NKC * NROW];
  __shared__ __align__(16) float h1s[2][KP][NBB];   // [parity][unit(pad)][batch]
  __shared__ __align__(16) float h2s[2][KP][NBB];
  __shared__ __align__(16) float xs[TSEEN][NBB];
  __shared__ __align__(16) float parts[2][4][NBB];  // [parity][unit-group][batch]

  const int tid  = threadIdx.x;
  const int wv   = tid >> 6;
  const int lane = tid & 63;
  const int q    = lane & 3;        // gate index for dots; batch slot for state
  const int ul   = lane >> 2;       // unit-local 0..15
  const int uw   = wv & 3;          // unit group 0..3
  const int bh   = wv >> 2;         // batch half 0..1
  const int u    = uw * 16 + ul;    // unit 0..63 (51 active)
  const bool on  = (u < H);
  const int uc   = on ? u : (H - 1);
  const int r    = q * H + uc;      // gate row 0..203
  const int baseb = blockIdx.x * NBB;
  const bool q1 = (q == 1), q2 = (q == 2), q3 = (q == 3);

  // ---- stage all three weight matrices into LDS (k padded to 52) ----
  for (int i = tid; i < 3 * NROW * KP; i += THREADS) {
    int m   = i / (NROW * KP);
    int rem = i - m * (NROW * KP);
    int rr  = rem / KP;
    int k   = rem - rr * KP;
    const float* src = (m == 0) ? Whh1 : (m == 1) ? Wih2 : Whh2;
    float v = (k < H) ? src[rr * H + k] : 0.f;
    ((float*)&WL[(m * NKC + (k >> 2)) * NROW + rr])[k & 3] = v;
  }

  // ---- stage inputs transposed: xs[t][b] (coalesced global reads) ----
  for (int i = tid; i < NBB * TSEEN; i += THREADS) {
    int b = i >> 8, t = i & 255;
    xs[t][b] = inp[(size_t)(baseb + b) * TSEEN + t];
  }

  // ---- zero h state (both parities; pad unit row stays 0) ----
  for (int i = tid; i < 2 * KP * NBB; i += THREADS) {
    (&h1s[0][0][0])[i] = 0.f;
    (&h2s[0][0][0])[i] = 0.f;
  }

  // ---- per-thread scalars ----
  const float wx = Wih1[r];
  const float b1 = bih1[r] + bhh1[r];
  const float b2 = bih2[r] + bhh2[r];
  const float wl = on ? Wlin[uc] : 0.f;
  const float bl = blin[0];

  float c1 = 0.f, c2 = 0.f;        // cell state for batch (bh*4 + q)
  float4 fbv = {0.f, 0.f, 0.f, 0.f};

  __syncthreads();

  #pragma unroll 1
  for (int t = 0; t < TTOT; ++t) {
    const int pw = t & 1;      // write parity
    const int pr = pw ^ 1;     // read parity

    float4 xv;
    if (t < TSEEN) xv = *(const float4*)&xs[t][bh * 4];
    else           xv = fbv;

    // ============== layer 1: a = b1 + wx*x + Whh1[r] . h1(t-1) ==============
    v2f a01 = {b1, b1}, a23 = {b1, b1};
    v2f s01 = {0.f, 0.f}, s23 = {0.f, 0.f};
    FMA2(a01, wx, xv.x, xv.y);
    FMA2(a23, wx, xv.z, xv.w);
    #pragma unroll
    for (int kc = 0; kc < NKC; ++kc) {
      float4 w  = WL[kc * NROW + r];
      float4 h0 = *(const float4*)&h1s[pr][kc * 4 + 0][bh * 4];
      float4 h1v = *(const float4*)&h1s[pr][kc * 4 + 1][bh * 4];
      float4 h2v = *(const float4*)&h1s[pr][kc * 4 + 2][bh * 4];
      float4 h3v = *(const float4*)&h1s[pr][kc * 4 + 3][bh * 4];
      FMA2(a01, w.x, h0.x,  h0.y);  FMA2(a23, w.x, h0.z,  h0.w);
      FMA2(s01, w.y, h1v.x, h1v.y); FMA2(s23, w.y, h1v.z, h1v.w);
      FMA2(a01, w.z, h2v.x, h2v.y); FMA2(a23, w.z, h2v.z, h2v.w);
      FMA2(s01, w.w, h3v.x, h3v.y); FMA2(s23, w.w, h3v.z, h3v.w);
    }
    a01 += s01; a23 += s23;

    float gi, gf, gg, go;
    gates_for_batch(a01, a23, q1, q2, q3, gi, gf, gg, go);
    float iv = fast_sig(gi), fv = fast_sig(gf);
    float gv = fast_tanh(gg), ov = fast_sig(go);
    c1 = fmaf(fv, c1, iv * gv);
    float h1n = ov * fast_tanh(c1);
    if (on) h1s[pw][u][bh * 4 + q] = h1n;

    __syncthreads();   // barrier A — the only per-step barrier (seen phase)

    // deferred output: out(t-1) for t-1 in [0, 254]
    if (t >= 1 && t <= TSEEN - 1 && tid < NBB) {
      float s = parts[pr][0][tid] + parts[pr][1][tid] +
                parts[pr][2][tid] + parts[pr][3][tid] + bl;
      out[(size_t)(baseb + tid) * TTOT + (t - 1)] = s;
    }

    // ========= layer 2: a = b2 + Wih2[r] . h1(t) + Whh2[r] . h2(t-1) =========
    v2f p01 = {b2, b2}, p23 = {b2, b2};
    v2f r01 = {0.f, 0.f}, r23 = {0.f, 0.f};
    #pragma unroll
    for (int kc = 0; kc < NKC; ++kc) {
      float4 w2 = WL[(NKC + kc) * NROW + r];
      float4 w3 = WL[(2 * NKC + kc) * NROW + r];
      float4 ha0 = *(const float4*)&h1s[pw][kc * 4 + 0][bh * 4];
      float4 ha1 = *(const float4*)&h1s[pw][kc * 4 + 1][bh * 4];
      float4 ha2 = *(const float4*)&h1s[pw][kc * 4 + 2][bh * 4];
      float4 ha3 = *(const float4*)&h1s[pw][kc * 4 + 3][bh * 4];
      float4 hb0 = *(const float4*)&h2s[pr][kc * 4 + 0][bh * 4];
      float4 hb1 = *(const float4*)&h2s[pr][kc * 4 + 1][bh * 4];
      float4 hb2 = *(const float4*)&h2s[pr][kc * 4 + 2][bh * 4];
      float4 hb3 = *(const float4*)&h2s[pr][kc * 4 + 3][bh * 4];
      FMA2(p01, w2.x, ha0.x, ha0.y); FMA2(p23, w2.x, ha0.z, ha0.w);
      FMA2(r01, w2.y, ha1.x, ha1.y); FMA2(r23, w2.y, ha1.z, ha1.w);
      FMA2(p01, w2.z, ha2.x, ha2.y); FMA2(p23, w2.z, ha2.z, ha2.w);
      FMA2(r01, w2.w, ha3.x, ha3.y); FMA2(r23, w2.w, ha3.z, ha3.w);
      FMA2(p01, w3.x, hb0.x, hb0.y); FMA2(p23, w3.x, hb0.z, hb0.w);
      FMA2(r01, w3.y, hb1.x, hb1.y); FMA2(r23, w3.y, hb1.z, hb1.w);
      FMA2(p01, w3.z, hb2.x, hb2.y); FMA2(p23, w3.z, hb2.z, hb2.w);
      FMA2(r01, w3.w, hb3.x, hb3.y); FMA2(r23, w3.w, hb3.z, hb3.w);
    }
    p01 += r01; p23 += r23;

    gates_for_batch(p01, p23, q1, q2, q3, gi, gf, gg, go);
    iv = fast_sig(gi); fv = fast_sig(gf);
    gv = fast_tanh(gg); ov = fast_sig(go);
    c2 = fmaf(fv, c2, iv * gv);
    float h2n = ov * fast_tanh(c2);

    // ---- linear head: per-lane (one batch), butterfly over units ----
    float pv = wl * h2n;
    pv += __shfl_xor(pv, 4, 64);
    pv += __shfl_xor(pv, 8, 64);
    pv += __shfl_xor(pv, 16, 64);
    pv += __shfl_xor(pv, 32, 64);
    if (ul == 0) parts[pw][uw][bh * 4 + q] = pv;   // lanes 0..3 of each wave
    if (on) h2s[pw][u][bh * 4 + q] = h2n;

    // feedback phase: x(t+1) = out(t); also emit outs 255..271
    if (t >= TSEEN - 1) {
      __syncthreads();   // barrier B (17 steps only)
      float4 p0 = *(const float4*)&parts[pw][0][bh * 4];
      float4 p1 = *(const float4*)&parts[pw][1][bh * 4];
      float4 p2 = *(const float4*)&parts[pw][2][bh * 4];
      float4 p3 = *(const float4*)&parts[pw][3][bh * 4];
      fbv.x = p0.x + p1.x + p2.x + p3.x + bl;
      fbv.y = p0.y + p1.y + p2.y + p3.y + bl;
      fbv.z = p0.z + p1.z + p2.z + p3.z + bl;
      fbv.w = p0.w + p1.w + p2.w + p3.w + bl;
      if (tid < NBB) {
        float s = parts[pw][0][tid] + parts[pw][1][tid] +
                  parts[pw][2][tid] + parts[pw][3][tid] + bl;
        out[(size_t)(baseb + tid) * TTOT + t] = s;
      }
    }
  }
}

extern "C" void kernel_launch(void* const* d_in, const int* in_sizes, int n_in,
                              void* d_out, int out_size, void* d_ws, size_t ws_size,
                              hipStream_t stream) {
  (void)in_sizes; (void)n_in; (void)d_ws; (void)ws_size; (void)out_size;
  const float* inp  = (const float*)d_in[0];
  const float* Wih1 = (const float*)d_in[1];
  const float* bih1 = (const float*)d_in[2];
  const float* Whh1 = (const float*)d_in[3];
  const float* bhh1 = (const float*)d_in[4];
  const float* Wih2 = (const float*)d_in[5];
  const float* bih2 = (const float*)d_in[6];
  const float* Whh2 = (const float*)d_in[7];
  const float* bhh2 = (const float*)d_in[8];
  const float* Wlin = (const float*)d_in[9];
  const float* blin = (const float*)d_in[10];
  float* outp = (float*)d_out;

  lstm2_kernel<<<NBLOCKS, THREADS, 0, stream>>>(
      inp, Wih1, bih1, Whh1, bhh1, Wih2, bih2, Whh2, bhh2, Wlin, blin, outp);
}